// Round 1
// baseline (284.641 us; speedup 1.0000x reference)
//
#include <hip/hip_runtime.h>
#include <hip/hip_bf16.h>

typedef __bf16 bf16_t;
typedef bf16_t bf16x8 __attribute__((ext_vector_type(8)));
typedef float f32x4 __attribute__((ext_vector_type(4)));

#define NB 4
#define SS 4096
#define DM 768
#define DH 64
#define NROW (NB * SS)   // 16384

// ---------------------------------------------------------------------------
// Kernel 1: transpose W_{Q,K,V} [768][64] fp32 -> Wt[3][64][768] bf16
// ---------------------------------------------------------------------------
__global__ __launch_bounds__(256) void wt_kernel(const float* __restrict__ wq,
                                                 const float* __restrict__ wk,
                                                 const float* __restrict__ wv,
                                                 bf16_t* __restrict__ wt) {
    int id = blockIdx.x * 256 + threadIdx.x;
    if (id >= 3 * DM * DH) return;
    int m = id / (DM * DH);
    int r = id - m * (DM * DH);
    int k = r >> 6;   // 0..767
    int c = r & 63;   // 0..63
    const float* w = (m == 0) ? wq : (m == 1) ? wk : wv;
    wt[(size_t)m * DH * DM + (size_t)c * DM + k] = (bf16_t)w[k * DH + c];
}

// ---------------------------------------------------------------------------
// Kernel 2: projections. One wave per 32 rows. Q,K row-major bf16; V transposed
// Vt[d][grow] so attention's PV B-operand is a contiguous 16B load.
// MFMA 16x16x32 bf16; A = x rows (fp32 loaded, converted), B = Wt (b128 loads).
// ---------------------------------------------------------------------------
__global__ __launch_bounds__(64) void proj_kernel(const float* __restrict__ x,
                                                  const bf16_t* __restrict__ wt,
                                                  bf16_t* __restrict__ Qo,
                                                  bf16_t* __restrict__ Ko,
                                                  bf16_t* __restrict__ Vt) {
    const int lane = threadIdx.x;
    const int l15 = lane & 15;
    const int lhi = lane >> 4;
    const int m0 = blockIdx.x * 32;   // 512 blocks * 32 rows = 16384

    f32x4 acc[2][12];
    #pragma unroll
    for (int fi = 0; fi < 2; fi++)
        #pragma unroll
        for (int n = 0; n < 12; n++)
            #pragma unroll
            for (int j = 0; j < 4; j++) acc[fi][n][j] = 0.0f;

    for (int k0 = 0; k0 < DM; k0 += 64) {
        // A fragments: x rows, fp32 -> bf16
        bf16x8 a[2][2];
        #pragma unroll
        for (int fi = 0; fi < 2; fi++) {
            #pragma unroll
            for (int kk = 0; kk < 2; kk++) {
                const float* src = x + (size_t)(m0 + fi * 16 + l15) * DM + k0 + kk * 32 + lhi * 8;
                f32x4 v0 = *reinterpret_cast<const f32x4*>(src);
                f32x4 v1 = *reinterpret_cast<const f32x4*>(src + 4);
                bf16x8 t;
                #pragma unroll
                for (int j = 0; j < 4; j++) { t[j] = (bf16_t)v0[j]; t[4 + j] = (bf16_t)v1[j]; }
                a[fi][kk] = t;
            }
        }
        // B fragments from Wt (contiguous 8 bf16 along k), reused across fi
        #pragma unroll
        for (int m = 0; m < 3; m++) {
            #pragma unroll
            for (int cj = 0; cj < 4; cj++) {
                #pragma unroll
                for (int kk = 0; kk < 2; kk++) {
                    bf16x8 bfr = *reinterpret_cast<const bf16x8*>(
                        wt + (size_t)m * DH * DM + (size_t)(cj * 16 + l15) * DM + k0 + kk * 32 + lhi * 8);
                    #pragma unroll
                    for (int fi = 0; fi < 2; fi++)
                        acc[fi][m * 4 + cj] = __builtin_amdgcn_mfma_f32_16x16x32_bf16(
                            a[fi][kk], bfr, acc[fi][m * 4 + cj], 0, 0, 0);
                }
            }
        }
    }

    // Epilogue: C/D layout row=(lane>>4)*4+reg, col=lane&15 (verified m89/m91)
    #pragma unroll
    for (int fi = 0; fi < 2; fi++) {
        #pragma unroll
        for (int cj = 0; cj < 4; cj++) {
            #pragma unroll
            for (int j = 0; j < 4; j++) {
                int row = m0 + fi * 16 + lhi * 4 + j;
                int col = cj * 16 + l15;
                Qo[(size_t)row * DH + col] = (bf16_t)acc[fi][cj][j];
                Ko[(size_t)row * DH + col] = (bf16_t)acc[fi][4 + cj][j];
                Vt[(size_t)col * NROW + row] = (bf16_t)acc[fi][8 + cj][j];
            }
        }
    }
}

// ---------------------------------------------------------------------------
// Kernel 3: flash attention. 1 wave per block, 32 query rows, KV-tile = 64.
// K, Vt read directly from workspace (L2-resident, 1 MB/batch). P goes through
// a small per-wave LDS buffer to convert C-layout -> A-layout for PV.
// ---------------------------------------------------------------------------
__global__ __launch_bounds__(64) void attn_kernel(const bf16_t* __restrict__ Q,
                                                  const bf16_t* __restrict__ K,
                                                  const bf16_t* __restrict__ Vt,
                                                  float* __restrict__ out) {
    __shared__ bf16_t pw[32][80];   // +16-col pad keeps b128 alignment, breaks conflicts
    const int lane = threadIdx.x;
    const int l15 = lane & 15;
    const int lhi = lane >> 4;
    const int bx = blockIdx.x;           // 0..511
    const int b = bx & 3;
    const int tile = 127 - (bx >> 2);    // biggest causal tiles dispatched first
    const int q0 = tile * 32;            // query-row base within batch

    const bf16_t* Qb = Q + (size_t)b * SS * DH;
    const bf16_t* Kb = K + (size_t)b * SS * DH;

    // Q fragments, hoisted (reused every kv tile)
    bf16x8 aq[2][2];
    #pragma unroll
    for (int fi = 0; fi < 2; fi++)
        #pragma unroll
        for (int kk = 0; kk < 2; kk++)
            aq[fi][kk] = *reinterpret_cast<const bf16x8*>(
                Qb + (size_t)(q0 + fi * 16 + l15) * DH + kk * 32 + lhi * 8);

    f32x4 o[2][4];
    float mrow[2][4], lrow[2][4];
    #pragma unroll
    for (int fi = 0; fi < 2; fi++)
        #pragma unroll
        for (int j = 0; j < 4; j++) { mrow[fi][j] = -1e30f; lrow[fi][j] = 0.0f; }
    #pragma unroll
    for (int fi = 0; fi < 2; fi++)
        #pragma unroll
        for (int cj = 0; cj < 4; cj++)
            #pragma unroll
            for (int j = 0; j < 4; j++) o[fi][cj][j] = 0.0f;

    const float cscale = 0.125f * 1.44269504088896341f;  // 1/sqrt(64) * log2(e)
    const int nkv = (q0 + 31) / 64 + 1;

    for (int kt = 0; kt < nkv; kt++) {
        const int kv0 = kt * 64;

        // S = Q K^T  (A = Q rows, B[d][kv] = K[kv][d] contiguous along d)
        f32x4 s[2][4];
        #pragma unroll
        for (int fi = 0; fi < 2; fi++)
            #pragma unroll
            for (int cj = 0; cj < 4; cj++)
                #pragma unroll
                for (int j = 0; j < 4; j++) s[fi][cj][j] = 0.0f;
        #pragma unroll
        for (int cj = 0; cj < 4; cj++) {
            #pragma unroll
            for (int kk = 0; kk < 2; kk++) {
                bf16x8 bk = *reinterpret_cast<const bf16x8*>(
                    Kb + (size_t)(kv0 + cj * 16 + l15) * DH + kk * 32 + lhi * 8);
                #pragma unroll
                for (int fi = 0; fi < 2; fi++)
                    s[fi][cj] = __builtin_amdgcn_mfma_f32_16x16x32_bf16(aq[fi][kk], bk, s[fi][cj], 0, 0, 0);
            }
        }

        // scale (base-2) + causal mask
        #pragma unroll
        for (int fi = 0; fi < 2; fi++) {
            #pragma unroll
            for (int cj = 0; cj < 4; cj++) {
                int col = kv0 + cj * 16 + l15;
                #pragma unroll
                for (int j = 0; j < 4; j++) {
                    int row = q0 + fi * 16 + lhi * 4 + j;
                    float t = s[fi][cj][j] * cscale;
                    s[fi][cj][j] = (col > row) ? -1e30f : t;
                }
            }
        }

        // row max: local over cj, then xor-reduce over the 16 lanes of the row
        float pm[2][4];
        #pragma unroll
        for (int fi = 0; fi < 2; fi++)
            #pragma unroll
            for (int j = 0; j < 4; j++)
                pm[fi][j] = fmaxf(fmaxf(s[fi][0][j], s[fi][1][j]), fmaxf(s[fi][2][j], s[fi][3][j]));
        #pragma unroll
        for (int off = 1; off < 16; off <<= 1)
            #pragma unroll
            for (int fi = 0; fi < 2; fi++)
                #pragma unroll
                for (int j = 0; j < 4; j++)
                    pm[fi][j] = fmaxf(pm[fi][j], __shfl_xor(pm[fi][j], off, 64));

        // online-softmax update
        float fac[2][4];
        #pragma unroll
        for (int fi = 0; fi < 2; fi++)
            #pragma unroll
            for (int j = 0; j < 4; j++) {
                float mn = fmaxf(mrow[fi][j], pm[fi][j]);
                fac[fi][j] = exp2f(mrow[fi][j] - mn);
                mrow[fi][j] = mn;
            }

        float ls[2][4];
        #pragma unroll
        for (int fi = 0; fi < 2; fi++)
            #pragma unroll
            for (int j = 0; j < 4; j++) ls[fi][j] = 0.0f;
        #pragma unroll
        for (int fi = 0; fi < 2; fi++)
            #pragma unroll
            for (int cj = 0; cj < 4; cj++)
                #pragma unroll
                for (int j = 0; j < 4; j++) {
                    float p = exp2f(s[fi][cj][j] - mrow[fi][j]);
                    s[fi][cj][j] = p;
                    ls[fi][j] += p;
                }
        #pragma unroll
        for (int off = 1; off < 16; off <<= 1)
            #pragma unroll
            for (int fi = 0; fi < 2; fi++)
                #pragma unroll
                for (int j = 0; j < 4; j++)
                    ls[fi][j] += __shfl_xor(ls[fi][j], off, 64);
        #pragma unroll
        for (int fi = 0; fi < 2; fi++)
            #pragma unroll
            for (int j = 0; j < 4; j++) lrow[fi][j] = lrow[fi][j] * fac[fi][j] + ls[fi][j];

        // rescale O
        #pragma unroll
        for (int fi = 0; fi < 2; fi++)
            #pragma unroll
            for (int cj = 0; cj < 4; cj++)
                #pragma unroll
                for (int j = 0; j < 4; j++) o[fi][cj][j] *= fac[fi][j];

        // P: C-layout -> LDS -> A-layout (same-wave cross-lane; rule #18 fences)
        asm volatile("s_waitcnt lgkmcnt(0)" ::: "memory");
        __builtin_amdgcn_sched_barrier(0);
        #pragma unroll
        for (int fi = 0; fi < 2; fi++)
            #pragma unroll
            for (int cj = 0; cj < 4; cj++)
                #pragma unroll
                for (int j = 0; j < 4; j++)
                    pw[fi * 16 + lhi * 4 + j][cj * 16 + l15] = (bf16_t)s[fi][cj][j];
        asm volatile("s_waitcnt lgkmcnt(0)" ::: "memory");
        __builtin_amdgcn_sched_barrier(0);

        bf16x8 pa[2][2];
        #pragma unroll
        for (int fi = 0; fi < 2; fi++)
            #pragma unroll
            for (int kk = 0; kk < 2; kk++)
                pa[fi][kk] = *reinterpret_cast<const bf16x8*>(&pw[fi * 16 + l15][kk * 32 + lhi * 8]);

        // O += P V   (B[kv][d] = Vt[d][kv] contiguous along kv)
        #pragma unroll
        for (int cj = 0; cj < 4; cj++) {
            #pragma unroll
            for (int kk = 0; kk < 2; kk++) {
                bf16x8 bv = *reinterpret_cast<const bf16x8*>(
                    Vt + (size_t)(cj * 16 + l15) * NROW + (size_t)b * SS + kv0 + kk * 32 + lhi * 8);
                #pragma unroll
                for (int fi = 0; fi < 2; fi++)
                    o[fi][cj] = __builtin_amdgcn_mfma_f32_16x16x32_bf16(pa[fi][kk], bv, o[fi][cj], 0, 0, 0);
            }
        }
    }

    // epilogue: divide by softmax denom, write fp32
    float* ob = out + (size_t)b * SS * DH;
    #pragma unroll
    for (int fi = 0; fi < 2; fi++)
        #pragma unroll
        for (int cj = 0; cj < 4; cj++)
            #pragma unroll
            for (int j = 0; j < 4; j++) {
                int row = q0 + fi * 16 + lhi * 4 + j;
                ob[(size_t)row * DH + cj * 16 + l15] = o[fi][cj][j] / lrow[fi][j];
            }
}

// ---------------------------------------------------------------------------
extern "C" void kernel_launch(void* const* d_in, const int* in_sizes, int n_in,
                              void* d_out, int out_size, void* d_ws, size_t ws_size,
                              hipStream_t stream) {
    const float* x  = (const float*)d_in[0];
    const float* wq = (const float*)d_in[1];
    const float* wk = (const float*)d_in[2];
    const float* wv = (const float*)d_in[3];
    float* out = (float*)d_out;

    // ws layout (bf16 elements): Q[16384*64] | K[16384*64] | Vt[64*16384] | Wt[3*64*768]
    bf16_t* Qw = (bf16_t*)d_ws;
    bf16_t* Kw = Qw + (size_t)NROW * DH;
    bf16_t* Vt = Kw + (size_t)NROW * DH;
    bf16_t* Wt = Vt + (size_t)NROW * DH;

    hipLaunchKernelGGL(wt_kernel, dim3((3 * DM * DH + 255) / 256), dim3(256), 0, stream,
                       wq, wk, wv, Wt);
    hipLaunchKernelGGL(proj_kernel, dim3(NROW / 32), dim3(64), 0, stream,
                       x, Wt, Qw, Kw, Vt);
    hipLaunchKernelGGL(attn_kernel, dim3(NB * (SS / 32)), dim3(64), 0, stream,
                       Qw, Kw, Vt, out);
}

// Round 2
// 125.164 us; speedup vs baseline: 2.2741x; 2.2741x over previous
//
#include <hip/hip_runtime.h>
#include <hip/hip_bf16.h>

typedef __bf16 bf16_t;
typedef bf16_t bf16x8 __attribute__((ext_vector_type(8)));
typedef float f32x4 __attribute__((ext_vector_type(4)));

#define NB 4
#define SS 4096
#define DM 768
#define DH 64
#define NROW (NB * SS)   // 16384
#define WV 8             // waves per attn block (kv-split factor)

// ---------------------------------------------------------------------------
// Kernel 1: transpose W_{Q,K,V} [768][64] fp32 -> Wt[3][64][768] bf16
// ---------------------------------------------------------------------------
__global__ __launch_bounds__(256) void wt_kernel(const float* __restrict__ wq,
                                                 const float* __restrict__ wk,
                                                 const float* __restrict__ wv,
                                                 bf16_t* __restrict__ wt) {
    int id = blockIdx.x * 256 + threadIdx.x;
    if (id >= 3 * DM * DH) return;
    int m = id / (DM * DH);
    int r = id - m * (DM * DH);
    int k = r >> 6;   // 0..767
    int c = r & 63;   // 0..63
    const float* w = (m == 0) ? wq : (m == 1) ? wk : wv;
    wt[(size_t)m * DH * DM + (size_t)c * DM + k] = (bf16_t)w[k * DH + c];
}

// ---------------------------------------------------------------------------
// Kernel 2: projections. 4 waves/block: wave (wr,wc) does 16 rows x 96 cols.
// Block covers 32 rows x 192 cols, x rows read once (row reuse stays in L1/L2).
// 512 blocks x 4 waves = 2048 waves = 8/CU.
// ---------------------------------------------------------------------------
__global__ __launch_bounds__(256) void proj_kernel(const float* __restrict__ x,
                                                   const bf16_t* __restrict__ wt,
                                                   bf16_t* __restrict__ Qo,
                                                   bf16_t* __restrict__ Ko,
                                                   bf16_t* __restrict__ Vt) {
    const int lane = threadIdx.x & 63;
    const int wid = threadIdx.x >> 6;    // 0..3
    const int wr = wid & 1;              // row half
    const int wc = wid >> 1;             // col half
    const int l15 = lane & 15;
    const int lhi = lane >> 4;
    const int m0 = blockIdx.x * 32 + wr * 16;
    const int nbase = wc * 6;            // fragment ids [nbase, nbase+6)

    f32x4 acc[6];
    #pragma unroll
    for (int n = 0; n < 6; n++)
        #pragma unroll
        for (int j = 0; j < 4; j++) acc[n][j] = 0.0f;

    for (int k0 = 0; k0 < DM; k0 += 64) {
        bf16x8 a[2];
        #pragma unroll
        for (int kk = 0; kk < 2; kk++) {
            const float* src = x + (size_t)(m0 + l15) * DM + k0 + kk * 32 + lhi * 8;
            f32x4 v0 = *reinterpret_cast<const f32x4*>(src);
            f32x4 v1 = *reinterpret_cast<const f32x4*>(src + 4);
            bf16x8 t;
            #pragma unroll
            for (int j = 0; j < 4; j++) { t[j] = (bf16_t)v0[j]; t[4 + j] = (bf16_t)v1[j]; }
            a[kk] = t;
        }
        #pragma unroll
        for (int n = 0; n < 6; n++) {
            const int gn = nbase + n;
            const int m = gn >> 2;
            const int cj = gn & 3;
            #pragma unroll
            for (int kk = 0; kk < 2; kk++) {
                bf16x8 bfr = *reinterpret_cast<const bf16x8*>(
                    wt + (size_t)m * DH * DM + (size_t)(cj * 16 + l15) * DM + k0 + kk * 32 + lhi * 8);
                acc[n] = __builtin_amdgcn_mfma_f32_16x16x32_bf16(a[kk], bfr, acc[n], 0, 0, 0);
            }
        }
    }

    // C/D layout: row=(lane>>4)*4+reg, col=lane&15
    #pragma unroll
    for (int n = 0; n < 6; n++) {
        const int gn = nbase + n;
        const int m = gn >> 2;
        const int cj = gn & 3;
        #pragma unroll
        for (int j = 0; j < 4; j++) {
            int row = m0 + lhi * 4 + j;
            int col = cj * 16 + l15;
            if (m == 0)      Qo[(size_t)row * DH + col] = (bf16_t)acc[n][j];
            else if (m == 1) Ko[(size_t)row * DH + col] = (bf16_t)acc[n][j];
            else             Vt[(size_t)col * NROW + row] = (bf16_t)acc[n][j];
        }
    }
}

// ---------------------------------------------------------------------------
// Kernel 3: flash attention, kv-split. 8 waves/block share one 32-row q-tile;
// wave w takes kv-tiles w, w+8, ... with independent online softmax; block
// combines partials (m,l,O) through LDS at the end.
// 512 blocks x 8 waves = 4096 waves = 16/CU.
// ---------------------------------------------------------------------------
__global__ __launch_bounds__(512, 4) void attn_kernel(const bf16_t* __restrict__ Q,
                                                      const bf16_t* __restrict__ K,
                                                      const bf16_t* __restrict__ Vt,
                                                      float* __restrict__ out) {
    // Ob[WV][32][64] f32 (64 KB) overlays the per-wave pw buffers (WV*5120 B);
    // safe because a __syncthreads separates last pw use from first Ob write.
    __shared__ char smem[WV * 32 * 64 * 4];
    __shared__ float lm[WV][32], ll[WV][32], ff[WV][32], Lr[32];

    const int tid = threadIdx.x;
    const int lane = tid & 63;
    const int w = tid >> 6;              // wave id 0..7
    const int l15 = lane & 15;
    const int lhi = lane >> 4;
    const int bx = blockIdx.x;           // 0..511
    const int b = bx & 3;
    const int tile = 127 - (bx >> 2);    // biggest causal tiles first
    const int q0 = tile * 32;

    bf16_t* pw = (bf16_t*)(smem + (size_t)w * 5120);   // [32][80] per wave

    const bf16_t* Qb = Q + (size_t)b * SS * DH;
    const bf16_t* Kb = K + (size_t)b * SS * DH;

    // Q fragments, hoisted
    bf16x8 aq[2][2];
    #pragma unroll
    for (int fi = 0; fi < 2; fi++)
        #pragma unroll
        for (int kk = 0; kk < 2; kk++)
            aq[fi][kk] = *reinterpret_cast<const bf16x8*>(
                Qb + (size_t)(q0 + fi * 16 + l15) * DH + kk * 32 + lhi * 8);

    f32x4 o[2][4];
    float mrow[2][4], lrow[2][4];
    #pragma unroll
    for (int fi = 0; fi < 2; fi++)
        #pragma unroll
        for (int j = 0; j < 4; j++) { mrow[fi][j] = -1e30f; lrow[fi][j] = 0.0f; }
    #pragma unroll
    for (int fi = 0; fi < 2; fi++)
        #pragma unroll
        for (int cj = 0; cj < 4; cj++)
            #pragma unroll
            for (int j = 0; j < 4; j++) o[fi][cj][j] = 0.0f;

    const float cscale = 0.125f * 1.44269504088896341f;  // 1/sqrt(64)*log2(e)
    const int nkv = (tile >> 1) + 1;     // causal kv-tile count for this q-tile

    for (int kt = w; kt < nkv; kt += WV) {
        const int kv0 = kt * 64;

        f32x4 s[2][4];
        #pragma unroll
        for (int fi = 0; fi < 2; fi++)
            #pragma unroll
            for (int cj = 0; cj < 4; cj++)
                #pragma unroll
                for (int j = 0; j < 4; j++) s[fi][cj][j] = 0.0f;
        #pragma unroll
        for (int cj = 0; cj < 4; cj++) {
            #pragma unroll
            for (int kk = 0; kk < 2; kk++) {
                bf16x8 bk = *reinterpret_cast<const bf16x8*>(
                    Kb + (size_t)(kv0 + cj * 16 + l15) * DH + kk * 32 + lhi * 8);
                #pragma unroll
                for (int fi = 0; fi < 2; fi++)
                    s[fi][cj] = __builtin_amdgcn_mfma_f32_16x16x32_bf16(aq[fi][kk], bk, s[fi][cj], 0, 0, 0);
            }
        }

        // scale (base-2) + causal mask
        #pragma unroll
        for (int fi = 0; fi < 2; fi++) {
            #pragma unroll
            for (int cj = 0; cj < 4; cj++) {
                int col = kv0 + cj * 16 + l15;
                #pragma unroll
                for (int j = 0; j < 4; j++) {
                    int row = q0 + fi * 16 + lhi * 4 + j;
                    float t = s[fi][cj][j] * cscale;
                    s[fi][cj][j] = (col > row) ? -1e30f : t;
                }
            }
        }

        // row max
        float pm[2][4];
        #pragma unroll
        for (int fi = 0; fi < 2; fi++)
            #pragma unroll
            for (int j = 0; j < 4; j++)
                pm[fi][j] = fmaxf(fmaxf(s[fi][0][j], s[fi][1][j]), fmaxf(s[fi][2][j], s[fi][3][j]));
        #pragma unroll
        for (int off = 1; off < 16; off <<= 1)
            #pragma unroll
            for (int fi = 0; fi < 2; fi++)
                #pragma unroll
                for (int j = 0; j < 4; j++)
                    pm[fi][j] = fmaxf(pm[fi][j], __shfl_xor(pm[fi][j], off, 64));

        float fac[2][4];
        #pragma unroll
        for (int fi = 0; fi < 2; fi++)
            #pragma unroll
            for (int j = 0; j < 4; j++) {
                float mn = fmaxf(mrow[fi][j], pm[fi][j]);
                fac[fi][j] = exp2f(mrow[fi][j] - mn);
                mrow[fi][j] = mn;
            }

        float ls[2][4];
        #pragma unroll
        for (int fi = 0; fi < 2; fi++)
            #pragma unroll
            for (int j = 0; j < 4; j++) ls[fi][j] = 0.0f;
        #pragma unroll
        for (int fi = 0; fi < 2; fi++)
            #pragma unroll
            for (int cj = 0; cj < 4; cj++)
                #pragma unroll
                for (int j = 0; j < 4; j++) {
                    float p = exp2f(s[fi][cj][j] - mrow[fi][j]);
                    s[fi][cj][j] = p;
                    ls[fi][j] += p;
                }
        #pragma unroll
        for (int off = 1; off < 16; off <<= 1)
            #pragma unroll
            for (int fi = 0; fi < 2; fi++)
                #pragma unroll
                for (int j = 0; j < 4; j++)
                    ls[fi][j] += __shfl_xor(ls[fi][j], off, 64);
        #pragma unroll
        for (int fi = 0; fi < 2; fi++)
            #pragma unroll
            for (int j = 0; j < 4; j++) lrow[fi][j] = lrow[fi][j] * fac[fi][j] + ls[fi][j];

        #pragma unroll
        for (int fi = 0; fi < 2; fi++)
            #pragma unroll
            for (int cj = 0; cj < 4; cj++)
                #pragma unroll
                for (int j = 0; j < 4; j++) o[fi][cj][j] *= fac[fi][j];

        // P: C-layout -> LDS -> A-layout (same-wave cross-lane; rule #18 fences)
        asm volatile("s_waitcnt lgkmcnt(0)" ::: "memory");
        __builtin_amdgcn_sched_barrier(0);
        #pragma unroll
        for (int fi = 0; fi < 2; fi++)
            #pragma unroll
            for (int cj = 0; cj < 4; cj++)
                #pragma unroll
                for (int j = 0; j < 4; j++)
                    pw[(fi * 16 + lhi * 4 + j) * 80 + cj * 16 + l15] = (bf16_t)s[fi][cj][j];
        asm volatile("s_waitcnt lgkmcnt(0)" ::: "memory");
        __builtin_amdgcn_sched_barrier(0);

        bf16x8 pa[2][2];
        #pragma unroll
        for (int fi = 0; fi < 2; fi++)
            #pragma unroll
            for (int kk = 0; kk < 2; kk++)
                pa[fi][kk] = *reinterpret_cast<const bf16x8*>(&pw[(fi * 16 + l15) * 80 + kk * 32 + lhi * 8]);

        #pragma unroll
        for (int cj = 0; cj < 4; cj++) {
            #pragma unroll
            for (int kk = 0; kk < 2; kk++) {
                bf16x8 bv = *reinterpret_cast<const bf16x8*>(
                    Vt + (size_t)(cj * 16 + l15) * NROW + (size_t)b * SS + kv0 + kk * 32 + lhi * 8);
                #pragma unroll
                for (int fi = 0; fi < 2; fi++)
                    o[fi][cj] = __builtin_amdgcn_mfma_f32_16x16x32_bf16(pa[fi][kk], bv, o[fi][cj], 0, 0, 0);
            }
        }
    }

    // ---- block combine of the WV partials ----
    __syncthreads();   // all waves done with pw before Ob overlays it

    float* Ob = (float*)smem;   // [WV][32][64]
    #pragma unroll
    for (int fi = 0; fi < 2; fi++)
        #pragma unroll
        for (int cj = 0; cj < 4; cj++)
            #pragma unroll
            for (int j = 0; j < 4; j++)
                Ob[((size_t)w * 32 + fi * 16 + lhi * 4 + j) * 64 + cj * 16 + l15] = o[fi][cj][j];
    if (l15 == 0) {
        #pragma unroll
        for (int fi = 0; fi < 2; fi++)
            #pragma unroll
            for (int j = 0; j < 4; j++) {
                lm[w][fi * 16 + lhi * 4 + j] = mrow[fi][j];
                ll[w][fi * 16 + lhi * 4 + j] = lrow[fi][j];
            }
    }
    __syncthreads();

    if (tid < 32) {
        const int row = tid;
        float M = -1e30f;
        #pragma unroll
        for (int ww = 0; ww < WV; ww++) M = fmaxf(M, lm[ww][row]);
        float Ls = 0.0f;
        #pragma unroll
        for (int ww = 0; ww < WV; ww++) {
            float f = exp2f(lm[ww][row] - M);
            ff[ww][row] = f;
            Ls += ll[ww][row] * f;
        }
        Lr[row] = Ls;
    }
    __syncthreads();

    float* ob = out + ((size_t)b * SS + q0) * DH;
    #pragma unroll
    for (int k = 0; k < (32 * 64) / 512; k++) {
        int idx = k * 512 + tid;
        int row = idx >> 6;
        int col = idx & 63;
        float sacc = 0.0f;
        #pragma unroll
        for (int ww = 0; ww < WV; ww++)
            sacc += Ob[((size_t)ww * 32 + row) * 64 + col] * ff[ww][row];
        ob[(size_t)row * DH + col] = sacc / Lr[row];
    }
}

// ---------------------------------------------------------------------------
extern "C" void kernel_launch(void* const* d_in, const int* in_sizes, int n_in,
                              void* d_out, int out_size, void* d_ws, size_t ws_size,
                              hipStream_t stream) {
    const float* x  = (const float*)d_in[0];
    const float* wq = (const float*)d_in[1];
    const float* wk = (const float*)d_in[2];
    const float* wv = (const float*)d_in[3];
    float* out = (float*)d_out;

    // ws layout (bf16): Q[16384*64] | K[16384*64] | Vt[64*16384] | Wt[3*64*768]
    bf16_t* Qw = (bf16_t*)d_ws;
    bf16_t* Kw = Qw + (size_t)NROW * DH;
    bf16_t* Vt = Kw + (size_t)NROW * DH;
    bf16_t* Wt = Vt + (size_t)NROW * DH;

    hipLaunchKernelGGL(wt_kernel, dim3((3 * DM * DH + 255) / 256), dim3(256), 0, stream,
                       wq, wk, wv, Wt);
    hipLaunchKernelGGL(proj_kernel, dim3(NROW / 32), dim3(256), 0, stream,
                       x, Wt, Qw, Kw, Vt);
    hipLaunchKernelGGL(attn_kernel, dim3(NB * (SS / 32)), dim3(512), 0, stream,
                       Qw, Kw, Vt, out);
}

// Round 3
// 122.865 us; speedup vs baseline: 2.3167x; 1.0187x over previous
//
#include <hip/hip_runtime.h>
#include <hip/hip_bf16.h>

typedef __bf16 bf16_t;
typedef bf16_t bf16x8 __attribute__((ext_vector_type(8)));
typedef bf16_t bf16x4 __attribute__((ext_vector_type(4)));
typedef float f32x4 __attribute__((ext_vector_type(4)));
typedef unsigned int u32;

#define NB 4
#define SS 4096
#define DM 768
#define DH 64
#define NROW (NB * SS)   // 16384
#define WV 8             // waves per attn block (kv-split factor)
#define CSCALE (0.125f * 1.44269504088896341f)   // 1/sqrt(64) * log2(e)

// ---------------------------------------------------------------------------
// Kernel 1: transpose W_{Q,K,V} [768][64] fp32 -> Wt[3][64][768] bf16
// ---------------------------------------------------------------------------
__global__ __launch_bounds__(256) void wt_kernel(const float* __restrict__ wq,
                                                 const float* __restrict__ wk,
                                                 const float* __restrict__ wv,
                                                 bf16_t* __restrict__ wt) {
    int id = blockIdx.x * 256 + threadIdx.x;
    if (id >= 3 * DM * DH) return;
    int m = id / (DM * DH);
    int r = id - m * (DM * DH);
    int k = r >> 6;
    int c = r & 63;
    const float* w = (m == 0) ? wq : (m == 1) ? wk : wv;
    wt[(size_t)m * DH * DM + (size_t)c * DM + k] = (bf16_t)w[k * DH + c];
}

// ---------------------------------------------------------------------------
// Kernel 2: projections. 1024 blocks x 4 waves; block = 16 rows x 192 cols,
// wave = 16 rows x 48 cols (3 of 12 col-fragments). Q written PRE-SCALED by
// 1/8*log2(e) so attention's softmax works directly in base-2 domain.
// ---------------------------------------------------------------------------
__global__ __launch_bounds__(256) void proj_kernel(const float* __restrict__ x,
                                                   const bf16_t* __restrict__ wt,
                                                   bf16_t* __restrict__ Qo,
                                                   bf16_t* __restrict__ Ko,
                                                   bf16_t* __restrict__ Vt) {
    const int lane = threadIdx.x & 63;
    const int wid = threadIdx.x >> 6;    // 0..3
    const int l15 = lane & 15;
    const int g = lane >> 4;
    const int m0 = blockIdx.x * 16;

    f32x4 acc[3];
    #pragma unroll
    for (int n = 0; n < 3; n++)
        #pragma unroll
        for (int j = 0; j < 4; j++) acc[n][j] = 0.0f;

    for (int k0 = 0; k0 < DM; k0 += 64) {
        bf16x8 a[2];
        #pragma unroll
        for (int kk = 0; kk < 2; kk++) {
            const float* src = x + (size_t)(m0 + l15) * DM + k0 + kk * 32 + g * 8;
            f32x4 v0 = *reinterpret_cast<const f32x4*>(src);
            f32x4 v1 = *reinterpret_cast<const f32x4*>(src + 4);
            bf16x8 t;
            #pragma unroll
            for (int j = 0; j < 4; j++) { t[j] = (bf16_t)v0[j]; t[4 + j] = (bf16_t)v1[j]; }
            a[kk] = t;
        }
        #pragma unroll
        for (int n = 0; n < 3; n++) {
            const int gn = wid * 3 + n;
            const int m = gn >> 2;
            const int cj = gn & 3;
            #pragma unroll
            for (int kk = 0; kk < 2; kk++) {
                bf16x8 bfr = *reinterpret_cast<const bf16x8*>(
                    wt + (size_t)m * DH * DM + (size_t)(cj * 16 + l15) * DM + k0 + kk * 32 + g * 8);
                acc[n] = __builtin_amdgcn_mfma_f32_16x16x32_bf16(a[kk], bfr, acc[n], 0, 0, 0);
            }
        }
    }

    #pragma unroll
    for (int n = 0; n < 3; n++) {
        const int gn = wid * 3 + n;
        const int m = gn >> 2;
        const int cj = gn & 3;
        #pragma unroll
        for (int j = 0; j < 4; j++) {
            int row = m0 + g * 4 + j;
            int col = cj * 16 + l15;
            float v = acc[n][j];
            if (m == 0)      Qo[(size_t)row * DH + col] = (bf16_t)(v * CSCALE);
            else if (m == 1) Ko[(size_t)row * DH + col] = (bf16_t)v;
            else             Vt[(size_t)col * NROW + row] = (bf16_t)v;
        }
    }
}

// ---------------------------------------------------------------------------
// Kernel 3: flash attention, swapped-operand form. 8 waves/block kv-split over
// one 32-row q-tile. S^T = mfma(K, Q): lane owns q = q0+fi*16+l15, holding 16
// kv values (cj,j) -> softmax is in-lane tree + 2 shfl_xor. PV computed as
// O^T = V^T P^T; P^T B-fragments built via 8 shfl + 4 select per (fi,kkc).
// No LDS in the main loop; 3-round tree combine in 33 KB LDS at the end.
// ---------------------------------------------------------------------------
__global__ __launch_bounds__(512, 4) void attn_kernel(const bf16_t* __restrict__ Q,
                                                      const bf16_t* __restrict__ K,
                                                      const bf16_t* __restrict__ Vt,
                                                      float* __restrict__ out) {
    __shared__ __align__(16) float Ob[4][2][4][4][16][4];  // [slot][fi][cjd][g][l15][j]
    __shared__ float Ml[4][2][2][16];                      // [slot][fi][m/l][l15]

    const int tid = threadIdx.x;
    const int lane = tid & 63;
    const int w = tid >> 6;
    const int l15 = lane & 15;
    const int g = lane >> 4;
    const int bx = blockIdx.x;
    const int b = bx & 3;
    const int tile = 127 - (bx >> 2);
    const int q0 = tile * 32;

    const bf16_t* Qb = Q + (size_t)b * SS * DH;
    const bf16_t* Kb = K + (size_t)b * SS * DH;

    // Q fragments (pre-scaled), hoisted; used as MFMA B operand (col = l15 = q)
    bf16x8 aq[2][2];
    #pragma unroll
    for (int fi = 0; fi < 2; fi++)
        #pragma unroll
        for (int kk = 0; kk < 2; kk++)
            aq[fi][kk] = *reinterpret_cast<const bf16x8*>(
                Qb + (size_t)(q0 + fi * 16 + l15) * DH + kk * 32 + g * 8);

    f32x4 o[2][4];        // O^T accumulator: row d = cjd*16+g*4+j, col q = l15
    float m_[2] = {-1e30f, -1e30f};
    float l_[2] = {0.0f, 0.0f};
    #pragma unroll
    for (int fi = 0; fi < 2; fi++)
        #pragma unroll
        for (int cjd = 0; cjd < 4; cjd++)
            #pragma unroll
            for (int j = 0; j < 4; j++) o[fi][cjd][j] = 0.0f;

    const int nkv = (tile >> 1) + 1;

    for (int kt = w; kt < nkv; kt += WV) {
        const int kv0 = kt * 64;

        // S^T = K Q^T : s[fi][cj] holds kv rows (g*4+j), q cols (l15)
        f32x4 s[2][4];
        #pragma unroll
        for (int fi = 0; fi < 2; fi++)
            #pragma unroll
            for (int cj = 0; cj < 4; cj++)
                #pragma unroll
                for (int j = 0; j < 4; j++) s[fi][cj][j] = 0.0f;
        #pragma unroll
        for (int cj = 0; cj < 4; cj++) {
            #pragma unroll
            for (int kk = 0; kk < 2; kk++) {
                bf16x8 kf = *reinterpret_cast<const bf16x8*>(
                    Kb + (size_t)(kv0 + cj * 16 + l15) * DH + kk * 32 + g * 8);
                #pragma unroll
                for (int fi = 0; fi < 2; fi++)
                    s[fi][cj] = __builtin_amdgcn_mfma_f32_16x16x32_bf16(kf, aq[fi][kk], s[fi][cj], 0, 0, 0);
            }
        }

        // causal mask (scale already folded into Q)
        #pragma unroll
        for (int fi = 0; fi < 2; fi++) {
            const int q = q0 + fi * 16 + l15;
            #pragma unroll
            for (int cj = 0; cj < 4; cj++) {
                const int kvb = kv0 + cj * 16 + g * 4;
                #pragma unroll
                for (int j = 0; j < 4; j++)
                    if (kvb + j > q) s[fi][cj][j] = -1e30f;
            }
        }

        // per-fi online softmax: in-lane tree + shfl_xor(16,32)
        u32 pb[2][4][2];
        float fac[2];
        #pragma unroll
        for (int fi = 0; fi < 2; fi++) {
            float c0 = fmaxf(fmaxf(s[fi][0][0], s[fi][0][1]), fmaxf(s[fi][0][2], s[fi][0][3]));
            float c1 = fmaxf(fmaxf(s[fi][1][0], s[fi][1][1]), fmaxf(s[fi][1][2], s[fi][1][3]));
            float c2 = fmaxf(fmaxf(s[fi][2][0], s[fi][2][1]), fmaxf(s[fi][2][2], s[fi][2][3]));
            float c3 = fmaxf(fmaxf(s[fi][3][0], s[fi][3][1]), fmaxf(s[fi][3][2], s[fi][3][3]));
            float mx = fmaxf(fmaxf(c0, c1), fmaxf(c2, c3));
            mx = fmaxf(mx, __shfl_xor(mx, 16));
            mx = fmaxf(mx, __shfl_xor(mx, 32));
            float mn = fmaxf(m_[fi], mx);
            fac[fi] = exp2f(m_[fi] - mn);
            m_[fi] = mn;

            #pragma unroll
            for (int cj = 0; cj < 4; cj++)
                #pragma unroll
                for (int j = 0; j < 4; j++)
                    s[fi][cj][j] = exp2f(s[fi][cj][j] - mn);

            float t0 = (s[fi][0][0] + s[fi][0][1]) + (s[fi][0][2] + s[fi][0][3]);
            float t1 = (s[fi][1][0] + s[fi][1][1]) + (s[fi][1][2] + s[fi][1][3]);
            float t2 = (s[fi][2][0] + s[fi][2][1]) + (s[fi][2][2] + s[fi][2][3]);
            float t3 = (s[fi][3][0] + s[fi][3][1]) + (s[fi][3][2] + s[fi][3][3]);
            float sum = (t0 + t1) + (t2 + t3);
            sum += __shfl_xor(sum, 16);
            sum += __shfl_xor(sum, 32);
            l_[fi] = l_[fi] * fac[fi] + sum;

            // pack P row to bf16: pb[fi][cj] = {j0|j1, j2|j3}
            #pragma unroll
            for (int cj = 0; cj < 4; cj++) {
                union { u32 w2[2]; bf16x4 v; } pu;
                #pragma unroll
                for (int j = 0; j < 4; j++) pu.v[j] = (bf16_t)s[fi][cj][j];
                pb[fi][cj][0] = pu.w2[0];
                pb[fi][cj][1] = pu.w2[1];
            }
        }

        // rescale O^T (col q = l15 matches m/l lane ownership — no redistribution)
        #pragma unroll
        for (int fi = 0; fi < 2; fi++)
            #pragma unroll
            for (int cjd = 0; cjd < 4; cjd++)
                #pragma unroll
                for (int j = 0; j < 4; j++) o[fi][cjd][j] *= fac[fi];

        // PV: O^T += V^T P^T. Build P^T B-fragment (k = kv = kkc*32+g*8+e) from
        // pb held at (same l15, lhi_s = 2(g&1)+{0,1}, cj_s = 2kkc+(g>>1)).
        const int srcA = l15 + ((lane >> 4) & 1) * 32;
        const int srcB = srcA + 16;
        const bool hicj = (lane >= 32);
        #pragma unroll
        for (int kkc = 0; kkc < 2; kkc++) {
            bf16x8 pf[2];
            #pragma unroll
            for (int fi = 0; fi < 2; fi++) {
                u32 a00 = (u32)__shfl((int)pb[fi][2 * kkc + 0][0], srcA);
                u32 a01 = (u32)__shfl((int)pb[fi][2 * kkc + 0][1], srcA);
                u32 a10 = (u32)__shfl((int)pb[fi][2 * kkc + 1][0], srcA);
                u32 a11 = (u32)__shfl((int)pb[fi][2 * kkc + 1][1], srcA);
                u32 b00 = (u32)__shfl((int)pb[fi][2 * kkc + 0][0], srcB);
                u32 b01 = (u32)__shfl((int)pb[fi][2 * kkc + 0][1], srcB);
                u32 b10 = (u32)__shfl((int)pb[fi][2 * kkc + 1][0], srcB);
                u32 b11 = (u32)__shfl((int)pb[fi][2 * kkc + 1][1], srcB);
                union { u32 w4[4]; bf16x8 v; } uu;
                uu.w4[0] = hicj ? a10 : a00;
                uu.w4[1] = hicj ? a11 : a01;
                uu.w4[2] = hicj ? b10 : b00;
                uu.w4[3] = hicj ? b11 : b01;
                pf[fi] = uu.v;
            }
            #pragma unroll
            for (int cjd = 0; cjd < 4; cjd++) {
                bf16x8 vf = *reinterpret_cast<const bf16x8*>(
                    Vt + (size_t)(cjd * 16 + l15) * NROW + (size_t)b * SS + kv0 + kkc * 32 + g * 8);
                #pragma unroll
                for (int fi = 0; fi < 2; fi++)
                    o[fi][cjd] = __builtin_amdgcn_mfma_f32_16x16x32_bf16(vf, pf[fi], o[fi][cjd], 0, 0, 0);
            }
        }
    }

    // ---- 3-round tree combine (4,2,1) ----
    #pragma unroll
    for (int r = WV / 2; r >= 1; r >>= 1) {
        if (w >= r && w < 2 * r) {
            const int s_ = w - r;
            #pragma unroll
            for (int fi = 0; fi < 2; fi++)
                #pragma unroll
                for (int cjd = 0; cjd < 4; cjd++)
                    *reinterpret_cast<f32x4*>(&Ob[s_][fi][cjd][g][l15][0]) = o[fi][cjd];
            if (lane < 16) {
                #pragma unroll
                for (int fi = 0; fi < 2; fi++) {
                    Ml[s_][fi][0][l15] = m_[fi];
                    Ml[s_][fi][1][l15] = l_[fi];
                }
            }
        }
        __syncthreads();
        if (w < r) {
            #pragma unroll
            for (int fi = 0; fi < 2; fi++) {
                float mb = Ml[w][fi][0][l15];
                float lb = Ml[w][fi][1][l15];
                float M = fmaxf(m_[fi], mb);
                float fa = exp2f(m_[fi] - M);
                float fb = exp2f(mb - M);
                l_[fi] = l_[fi] * fa + lb * fb;
                m_[fi] = M;
                #pragma unroll
                for (int cjd = 0; cjd < 4; cjd++) {
                    f32x4 ov = *reinterpret_cast<const f32x4*>(&Ob[w][fi][cjd][g][l15][0]);
                    o[fi][cjd] = o[fi][cjd] * fa + ov * fb;
                }
            }
        }
        __syncthreads();
    }

    if (w == 0) {
        float* ob = out + ((size_t)b * SS + q0) * DH;
        #pragma unroll
        for (int fi = 0; fi < 2; fi++) {
            float rl = 1.0f / l_[fi];
            #pragma unroll
            for (int cjd = 0; cjd < 4; cjd++) {
                f32x4 v = o[fi][cjd] * rl;
                *reinterpret_cast<f32x4*>(&ob[(size_t)(fi * 16 + l15) * DH + cjd * 16 + g * 4]) = v;
            }
        }
    }
}

// ---------------------------------------------------------------------------
extern "C" void kernel_launch(void* const* d_in, const int* in_sizes, int n_in,
                              void* d_out, int out_size, void* d_ws, size_t ws_size,
                              hipStream_t stream) {
    const float* x  = (const float*)d_in[0];
    const float* wq = (const float*)d_in[1];
    const float* wk = (const float*)d_in[2];
    const float* wv = (const float*)d_in[3];
    float* out = (float*)d_out;

    bf16_t* Qw = (bf16_t*)d_ws;
    bf16_t* Kw = Qw + (size_t)NROW * DH;
    bf16_t* Vt = Kw + (size_t)NROW * DH;
    bf16_t* Wt = Vt + (size_t)NROW * DH;

    hipLaunchKernelGGL(wt_kernel, dim3((3 * DM * DH + 255) / 256), dim3(256), 0, stream,
                       wq, wk, wv, Wt);
    hipLaunchKernelGGL(proj_kernel, dim3(NROW / 16), dim3(256), 0, stream,
                       x, Wt, Qw, Kw, Vt);
    hipLaunchKernelGGL(attn_kernel, dim3(NB * (SS / 32)), dim3(512), 0, stream,
                       Qw, Kw, Vt, out);
}